// Round 8
// baseline (169.624 us; speedup 1.0000x reference)
//
#include <hip/hip_runtime.h>
#include <hip/hip_bf16.h>

#define N_NODES 100000
#define N_EDGES 250000
#define EMB 32
#define TYPES 16
#define R2 100          // num relations
#define SB 1024
#define NB ((N_EDGES + SB - 1) / SB)    // 245
#define CAPD 16         // per-node slot capacity (max degree <= 16 verified by prior passes)

typedef __attribute__((ext_vector_type(8))) short short8;

// fp32 -> bf16 bits, round-to-nearest-even
__device__ __forceinline__ unsigned short f2bf_u(float f) {
    unsigned u = __float_as_uint(f);
    u = (u + 0x7fffu + ((u >> 16) & 1u)) >> 16;
    return (unsigned short)u;
}
// unpack bf16 pair from u32
__device__ __forceinline__ float bfl(unsigned u) { return __uint_as_float(u << 16); }
__device__ __forceinline__ float bfh(unsigned u) { return __uint_as_float(u & 0xffff0000u); }

// ---------------------------------------------------------------------------
// Pass 1 (no histogram, no LDS, no barriers):
//   Blocks [0,NB): per edge -> drank via dcnt atomic; scatter ONE uint2 to
//     dst-slot (d<<4)|drank:  {sid | r<<17,  s | r<<17}.
//   Blocks [NB,NB+R2): W pack, m-major bf16 col-pairs for coalesced group
//     reads:  pwc1[r*512 + m*16 + c] = {W1[r][m][2c], W1[r][m][2c+1]}
//             pwc2[r*256 + m*8  + c] = {W2[r][m][2c], W2[r][m][2c+1]}
__global__ __launch_bounds__(SB) void pass1_kernel(
        const int* __restrict__ etype, const int* __restrict__ edge_src,
        const int* __restrict__ edge_dst, const int* __restrict__ src_ids,
        const float* __restrict__ W1, const float* __restrict__ W2,
        int* __restrict__ dcnt,
        unsigned* __restrict__ pwc1, unsigned* __restrict__ pwc2,
        uint2* __restrict__ epackD) {
    int t = threadIdx.x, b = blockIdx.x;
    if (b < NB) {
        int e = b * SB + t;
        if (e < N_EDGES) {
            int r = etype[e];
            int d = edge_dst[e];
            int k = atomicAdd(&dcnt[d], 1);       // rank within dst (order free)
            if (k > CAPD - 1) k = CAPD - 1;       // safety clamp (unused in practice)
            int s = edge_src[e];
            int sid = src_ids[s];
            uint2 v = { (unsigned)sid | ((unsigned)r << 17),
                        (unsigned)s   | ((unsigned)r << 17) };
            epackD[(d << 4) | k] = v;
        }
    } else {
        int r = b - NB;
        if (t < 512) {                            // pwc1: m=t>>4 (0..31), c=t&15
            int m = t >> 4, c = t & 15;
            const float* Wr1 = W1 + (size_t)r * (EMB * EMB);
            unsigned lo = f2bf_u(Wr1[m * EMB + 2 * c]);
            unsigned hi = f2bf_u(Wr1[m * EMB + 2 * c + 1]);
            pwc1[(size_t)r * 512 + t] = lo | (hi << 16);
        } else if (t < 768) {                     // pwc2: m=(t-512)>>3, c=&7
            int idx = t - 512;
            int m = idx >> 3, c = idx & 7;
            const float* Wr2 = W2 + (size_t)r * (EMB * TYPES);
            unsigned lo = f2bf_u(Wr2[m * TYPES + 2 * c]);
            unsigned hi = f2bf_u(Wr2[m * TYPES + 2 * c + 1]);
            pwc2[(size_t)r * 256 + idx] = lo | (hi << 16);
        }
    }
}

// ---------------------------------------------------------------------------
// Fused layer1 + reduce1: 16 lanes per node, lane c owns output col-pair
// (2c, 2c+1). Cooperative 128B edge-record read, per-edge fp32 entity row
// gather (2x64B group-coalesced), 32-wide dot via shfl broadcast against the
// L2-resident m-major W1 stream. Mean + relu -> h1 bf16x2 in-register.
// No msg buffer, no second kernel.
__global__ __launch_bounds__(256) void fused1_kernel(
        const float* __restrict__ entity,
        const unsigned* __restrict__ pwc1,
        const int* __restrict__ dcnt,
        const uint2* __restrict__ epackD,
        unsigned* __restrict__ h1bf) {
    int tid = blockIdx.x * 256 + threadIdx.x;     // over N_NODES*16 exactly
    int nn = tid >> 4;
    if (nn >= N_NODES) return;
    int lane = threadIdx.x & 63;
    int base = lane & 48;                          // 16-lane group base
    int c = lane & 15;
    int cnt = dcnt[nn];
    int km = cnt < CAPD ? cnt : CAPD;
    uint2 E = epackD[(nn << 4) + c];               // my slot (garbage if c>=km: never shfl'd)
    float d0 = 0.f, d1 = 0.f;
    for (int k = 0; k < km; ++k) {
        unsigned ei = (unsigned)__shfl((int)E.x, base + k);
        int sid = (int)(ei & 0x1FFFFu);
        int r   = (int)(ei >> 17);
        const float* row = entity + (size_t)sid * EMB;
        float e0 = row[c];                         // elements 0..15 across group
        float e1 = row[c + 16];                    // elements 16..31
        const unsigned* wb = pwc1 + (size_t)r * 512;
#pragma unroll
        for (int m = 0; m < 32; ++m) {
            float a = __shfl(m < 16 ? e0 : e1, base + (m & 15));
            unsigned w = wb[m * 16 + c];           // 64B coalesced per group
            d0 += a * bfl(w);
            d1 += a * bfh(w);
        }
    }
    float inv = 1.0f / fmaxf((float)cnt, 1.0f);
    unsigned lo = f2bf_u(fmaxf(d0 * inv, 0.f));
    unsigned hi = f2bf_u(fmaxf(d1 * inv, 0.f));
    h1bf[(nn << 4) + c] = lo | (hi << 16);
}

// ---------------------------------------------------------------------------
// Fused layer2 + reduce2 + PonderNet head: 8 lanes per node, lane c owns
// output col-pair (2c, 2c+1). Gathers bf16 h1 rows (2x32B per group), dots
// against L2-resident W2 stream, mean, head, writes final fp32 output.
__global__ __launch_bounds__(256) void fused2_kernel(
        const unsigned* __restrict__ h1bf,
        const unsigned* __restrict__ pwc2,
        const int* __restrict__ dcnt,
        const uint2* __restrict__ epackD,
        const float* __restrict__ lw, const float* __restrict__ lb,
        float* __restrict__ out) {
    int tid = blockIdx.x * 256 + threadIdx.x;     // over N_NODES*8 exactly
    int nn = tid >> 3;
    if (nn >= N_NODES) return;
    int lane = threadIdx.x & 63;
    int base = lane & 56;                          // 8-lane group base
    int c = lane & 7;
    int cnt = dcnt[nn];
    int km = cnt < CAPD ? cnt : CAPD;
    uint2 Ea = epackD[(nn << 4) + c];              // slots c and c+8
    uint2 Eb = epackD[(nn << 4) + 8 + c];
    float d0 = 0.f, d1 = 0.f;
    for (int k = 0; k < km; ++k) {
        int sel = (k < 8) ? (int)Ea.y : (int)Eb.y; // k uniform per group
        unsigned ei = (unsigned)__shfl(sel, base + (k & 7));
        int s = (int)(ei & 0x1FFFFu);
        int r = (int)(ei >> 17);
        unsigned H0 = h1bf[(size_t)s * 16 + c];        // col-pairs 0..7
        unsigned H1 = h1bf[(size_t)s * 16 + 8 + c];    // col-pairs 8..15
        const unsigned* wb = pwc2 + (size_t)r * 256;
#pragma unroll
        for (int p = 0; p < 16; ++p) {             // input col-pair p -> elems 2p,2p+1
            unsigned hw = (unsigned)__shfl(p < 8 ? (int)H0 : (int)H1, base + (p & 7));
            float a0 = bfl(hw), a1 = bfh(hw);
            unsigned w0 = wb[(2 * p) * 8 + c];     // 32B coalesced per group
            unsigned w1 = wb[(2 * p + 1) * 8 + c];
            d0 += a0 * bfl(w0); d1 += a0 * bfh(w0);
            d0 += a1 * bfl(w1); d1 += a1 * bfh(w1);
        }
    }
    float inv = 1.0f / fmaxf((float)cnt, 1.0f);
    float h0 = d0 * inv, h1v = d1 * inv;
    float part = h0 * lw[2 * c] + h1v * lw[2 * c + 1];
    part += __shfl_xor(part, 1);
    part += __shfl_xor(part, 2);
    part += __shfl_xor(part, 4);
    float lam = 1.0f / (1.0f + expf(-(part + lb[0])));

    float2 hv = { h0, h1v };
    ((float2*)(out + (size_t)nn * TYPES))[c] = hv;
    ((float2*)(out + (size_t)N_NODES * TYPES + (size_t)nn * TYPES))[c] = hv;
    if (c == 0) {
        out[(size_t)2 * N_NODES * TYPES + nn] = lam;
        out[(size_t)2 * N_NODES * TYPES + N_NODES + nn] = 1.0f - lam;
    }
}

// ---------------------------------------------------------------------------
extern "C" void kernel_launch(void* const* d_in, const int* in_sizes, int n_in,
                              void* d_out, int out_size, void* d_ws, size_t ws_size,
                              hipStream_t stream) {
    const float* entity = (const float*)d_in[0];
    const float* W1     = (const float*)d_in[1];
    const float* W2     = (const float*)d_in[2];
    const float* lw     = (const float*)d_in[3];
    const float* lb     = (const float*)d_in[4];
    const int* src_ids  = (const int*)d_in[5];
    const int* edge_src = (const int*)d_in[6];
    const int* edge_dst = (const int*)d_in[7];
    const int* etype    = (const int*)d_in[8];
    float* out = (float*)d_out;

    // ws layout (u32 units, all 16B aligned)
    unsigned int* W = (unsigned int*)d_ws;
    int* dcnt       = (int*)(W + 0);           // 100,000  (zeroed)
    uint2* epackD   = (uint2*)(W + 100000);    // N_NODES*16 uint2 = 3.2M u32
    unsigned* pwc1  = W + 3300000;             // 100*512 = 51,200 u32 (200KB)
    unsigned* pwc2  = W + 3351200;             // 100*256 = 25,600 u32 (100KB)
    unsigned* h1bf  = W + 3376800;             // N_NODES*16 = 1.6M u32
    // total: 4,976,800 u32 = 19.9 MB

    (void)hipMemsetAsync(d_ws, 0, 100000 * sizeof(int), stream);   // dcnt only

    pass1_kernel<<<NB + R2, SB, 0, stream>>>(etype, edge_src, edge_dst, src_ids,
                                             W1, W2, dcnt, pwc1, pwc2, epackD);
    fused1_kernel<<<(N_NODES * 16) / 256, 256, 0, stream>>>(
        entity, pwc1, dcnt, epackD, h1bf);
    fused2_kernel<<<(N_NODES * 8) / 256, 256, 0, stream>>>(
        h1bf, pwc2, dcnt, epackD, lw, lb, out);
}

// Round 9
// 128.954 us; speedup vs baseline: 1.3154x; 1.3154x over previous
//
#include <hip/hip_runtime.h>
#include <hip/hip_bf16.h>

#define N_NODES 100000
#define N_EDGES 250000
#define EMB 32
#define TYPES 16
#define R2 100          // num relations
#define SB 1024
#define NB ((N_EDGES + SB - 1) / SB)    // 245
#define CAP 4096        // per-relation slot capacity (counts ~2500±50)
#define CAPD 16         // per-node slot capacity (Poisson(2.5): P(deg>16) ~ 1e-10)
#define S1 192          // stripes per relation, layer 1 (nT<=~163 -> 1 tile/wave)
#define S2 192          // stripes per relation, layer 2
#define LW 4            // waves per block in layer kernels (256 threads)

typedef __attribute__((ext_vector_type(8))) short short8;
typedef __attribute__((ext_vector_type(4))) float f32x4;

// fp32 -> bf16 bits, round-to-nearest-even
__device__ __forceinline__ unsigned short f2bf_u(float f) {
    unsigned u = __float_as_uint(f);
    u = (u + 0x7fffu + ((u >> 16) & 1u)) >> 16;
    return (unsigned short)u;
}
// unpack bf16 pair from u32
__device__ __forceinline__ float bfl(unsigned u) { return __uint_as_float(u << 16); }
__device__ __forceinline__ float bfh(unsigned u) { return __uint_as_float(u & 0xffff0000u); }

// ---------------------------------------------------------------------------
// Pass 1: blocks [0,NB) = edge scatter (LDS relation ranks + one global
// atomicAdd per (block,rel); dst slot = (d<<4)|drank via dcnt atomic).
// epack = 8B/edge: {sid | pd_lo15<<17, s | pd_hi6<<17}.
// Blocks [NB,NB+R2) = W1/W2 bf16 fragment packing (pw1 = column pairs).
__global__ __launch_bounds__(SB) void pass1_kernel(
        const int* __restrict__ etype, const int* __restrict__ edge_src,
        const int* __restrict__ edge_dst, const int* __restrict__ src_ids,
        const float* __restrict__ W1, const float* __restrict__ W2,
        int* __restrict__ rcnt, int* __restrict__ dcnt,
        unsigned short* __restrict__ pw1, unsigned short* __restrict__ pw2,
        uint2* __restrict__ epack) {
    int t = threadIdx.x, b = blockIdx.x;
    if (b < NB) {
        __shared__ int lh[R2];
        __shared__ int lbase[R2];
        if (t < R2) lh[t] = 0;
        __syncthreads();
        int e = b * SB + t;
        int r = 0, lrank = 0, pd = 0, s = 0, sid = 0;
        bool valid = e < N_EDGES;
        if (valid) {
            r = etype[e];
            lrank = atomicAdd(&lh[r], 1);           // rank within (chunk, rel)
            int d = edge_dst[e];
            int drank = atomicAdd(&dcnt[d], 1);     // global dst rank (order free)
            if (drank > CAPD - 1) drank = CAPD - 1; // safety clamp
            pd = (d << 4) | drank;                  // final msg slot, 21 bits
            s = edge_src[e];
            sid = src_ids[s];
        }
        __syncthreads();
        if (t < R2) {
            int c = lh[t];
            lbase[t] = c ? atomicAdd(&rcnt[t], c) : 0;
        }
        __syncthreads();
        if (valid) {
            uint2 v = { (unsigned)sid | (((unsigned)pd & 0x7FFFu) << 17),
                        (unsigned)s   | (((unsigned)pd >> 15) << 17) };
            epack[((size_t)r << 12) + lbase[r] + lrank] = v;
        }
    } else {
        int r = b - NB;
        // pack W1: b0 slot j<8 -> col 2n, b1 slot j>=8 -> col 2n+1; k = q*8+j
        const float* Wr1 = W1 + (size_t)r * (EMB * EMB);
        {
            int l = t >> 4, j = t & 15;
            int n = l & 15, q = l >> 4;
            int k = q * 8 + (j & 7);
            int col = (j < 8) ? (2 * n) : (2 * n + 1);
            pw1[(size_t)r * 1024 + t] = f2bf_u(Wr1[k * EMB + col]);
        }
        if (t < 512) {
            const float* Wr2 = W2 + (size_t)r * (EMB * TYPES);
            int l = t >> 3, j = t & 7;
            int n = l & 15, q = l >> 4;
            int k = q * 8 + j;
            pw2[(size_t)r * 512 + t] = f2bf_u(Wr2[k * TYPES + n]);
        }
    }
}

// ---------------------------------------------------------------------------
// Layer 1: S1=192 stripes -> ~1 tile per wave (maximize independent
// latency chains in flight). Gather entity rows fp32 (32B/lane), convert to
// bf16 in-register, 2 MFMA/tile (cols 2n/2n+1), coalesced u32 stores to msg1.
__global__ __launch_bounds__(64 * LW) void layer1_kernel(
        const float* __restrict__ entity,
        const unsigned short* __restrict__ pw1,
        const int* __restrict__ rcnt,
        const uint2* __restrict__ epack,
        unsigned int* __restrict__ msg1) {
    int r = blockIdx.x % R2, sg = blockIdx.x / R2;
    int lane = threadIdx.x & 63, w = threadIdx.x >> 6;
    int stripe = sg * LW + w;
    int cnt = rcnt[r];
    int nT = (cnt + 15) >> 4;
    int n = lane & 15, q = lane >> 4;
    const unsigned short* pw = pw1 + (size_t)r * 1024;
    short8 b0 = *(const short8*)(pw + lane * 16);
    short8 b1 = *(const short8*)(pw + lane * 16 + 8);
    const uint2* ep = epack + ((size_t)r << 12);
    for (int g = stripe; g < nT; g += S1) {
        int base = g * 16;
        int cl = cnt - base;
        int me = n < cl ? n : cl - 1;
        uint2 E = ep[base + me];
        int sid = (int)(E.x & 0x1FFFFu);
        int pd  = (int)((E.x >> 17) | ((E.y >> 17) << 15));
        const float4* ar = (const float4*)(entity + (size_t)sid * EMB + q * 8);
        float4 v0 = ar[0], v1 = ar[1];
        short8 a;
        a[0] = (short)f2bf_u(v0.x); a[1] = (short)f2bf_u(v0.y);
        a[2] = (short)f2bf_u(v0.z); a[3] = (short)f2bf_u(v0.w);
        a[4] = (short)f2bf_u(v1.x); a[5] = (short)f2bf_u(v1.y);
        a[6] = (short)f2bf_u(v1.z); a[7] = (short)f2bf_u(v1.w);
        f32x4 c0 = {0.f,0.f,0.f,0.f}, c1 = {0.f,0.f,0.f,0.f};
        c0 = __builtin_amdgcn_mfma_f32_16x16x32_bf16(a, b0, c0, 0, 0, 0);
        c1 = __builtin_amdgcn_mfma_f32_16x16x32_bf16(a, b1, c1, 0, 0, 0);
#pragma unroll
        for (int i = 0; i < 4; ++i) {
            int row = q * 4 + i;
            int p = __shfl(pd, row);            // lanes 0..15 hold rows 0..15
            if (row < cl) {
                unsigned wv = (unsigned)f2bf_u(c0[i]) | ((unsigned)f2bf_u(c1[i]) << 16);
                msg1[(size_t)p * 16 + n] = wv;  // cols (2n, 2n+1), coalesced
            }
        }
    }
}

// ---------------------------------------------------------------------------
// Segmented mean + relu -> h1 in bf16 (u32 = 2 cols). Sums in fp32.
// 4-way batched predicated loads: issue 4 independent row reads per
// iteration (index clamped to valid range, masked accumulate) so the
// latency chains overlap; 89% of nodes (km<=4) need one batch.
__global__ void reduce1_kernel(const unsigned int* __restrict__ msg1,
                               const int* __restrict__ dcnt,
                               unsigned int* __restrict__ h1bf) {
    int t = blockIdx.x * blockDim.x + threadIdx.x;   // over N_NODES*16
    if (t >= N_NODES * 16) return;
    int nn = t >> 4, cp = t & 15;
    int cnt = dcnt[nn];
    int km = cnt < CAPD ? cnt : CAPD;
    int s = nn << 4;
    float sx = 0.f, sy = 0.f;
    for (int k0 = 0; k0 < km; k0 += 4) {
        int kmax = km - 1;
        int i0 = k0,     c0 = i0 < kmax ? i0 : kmax;
        int i1 = k0 + 1, c1 = i1 < kmax ? i1 : kmax;
        int i2 = k0 + 2, c2 = i2 < kmax ? i2 : kmax;
        int i3 = k0 + 3, c3 = i3 < kmax ? i3 : kmax;
        unsigned v0 = msg1[(size_t)(s + c0) * 16 + cp];
        unsigned v1 = msg1[(size_t)(s + c1) * 16 + cp];
        unsigned v2 = msg1[(size_t)(s + c2) * 16 + cp];
        unsigned v3 = msg1[(size_t)(s + c3) * 16 + cp];
        float m1 = (i1 < km) ? 1.f : 0.f;
        float m2 = (i2 < km) ? 1.f : 0.f;
        float m3 = (i3 < km) ? 1.f : 0.f;
        sx += bfl(v0) + m1 * bfl(v1) + m2 * bfl(v2) + m3 * bfl(v3);
        sy += bfh(v0) + m1 * bfh(v1) + m2 * bfh(v2) + m3 * bfh(v3);
    }
    float inv = 1.0f / fmaxf((float)cnt, 1.0f);
    unsigned lo = f2bf_u(fmaxf(sx * inv, 0.f));
    unsigned hi = f2bf_u(fmaxf(sy * inv, 0.f));
    h1bf[t] = lo | (hi << 16);
}

// ---------------------------------------------------------------------------
// Layer 2: S2=192 stripes (~1 tile/wave). Gather bf16 h1 rows (16B/lane),
// 1 MFMA/tile; column pairing via shfl_xor -> one u32 store per even lane-row.
__global__ __launch_bounds__(64 * LW) void layer2_kernel(
        const unsigned short* __restrict__ h1bf,
        const unsigned short* __restrict__ pw2,
        const int* __restrict__ rcnt,
        const uint2* __restrict__ epack,
        unsigned int* __restrict__ msg2) {
    int r = blockIdx.x % R2, sg = blockIdx.x / R2;
    int lane = threadIdx.x & 63, w = threadIdx.x >> 6;
    int stripe = sg * LW + w;
    int cnt = rcnt[r];
    int nT = (cnt + 15) >> 4;
    int n = lane & 15, q = lane >> 4;
    short8 b = *(const short8*)(pw2 + (size_t)r * 512 + lane * 8);
    const uint2* ep = epack + ((size_t)r << 12);
    for (int g = stripe; g < nT; g += S2) {
        int base = g * 16;
        int cl = cnt - base;
        int me = n < cl ? n : cl - 1;
        uint2 E = ep[base + me];
        int s  = (int)(E.y & 0x1FFFFu);
        int pd = (int)((E.x >> 17) | ((E.y >> 17) << 15));
        short8 a = *(const short8*)(h1bf + (size_t)s * EMB + q * 8);
        f32x4 c = {0.f,0.f,0.f,0.f};
        c = __builtin_amdgcn_mfma_f32_16x16x32_bf16(a, b, c, 0, 0, 0);
#pragma unroll
        for (int i = 0; i < 4; ++i) {
            int row = q * 4 + i;
            int p = __shfl(pd, row);
            unsigned myb = (unsigned)f2bf_u(c[i]);
            unsigned ob  = (unsigned)__shfl_xor((int)myb, 1);
            if (row < cl && !(n & 1)) {
                msg2[(size_t)p * 8 + (n >> 1)] = myb | (ob << 16);  // cols (n, n+1)
            }
        }
    }
}

// ---------------------------------------------------------------------------
// Segmented mean + PonderNet head, fused; 2-way batched row loads (4x uint4
// in flight per iteration); writes final fp32 output.
__global__ void reduce2_head_kernel(const unsigned int* __restrict__ msg2,
                                    const int* __restrict__ dcnt,
                                    const float* __restrict__ lw,
                                    const float* __restrict__ lb,
                                    float* __restrict__ out) {
    int nn = blockIdx.x * blockDim.x + threadIdx.x;
    if (nn >= N_NODES) return;
    int cnt = dcnt[nn];
    int km = cnt < CAPD ? cnt : CAPD;
    int s = nn << 4;
    float h[TYPES];
#pragma unroll
    for (int j = 0; j < TYPES; ++j) h[j] = 0.f;
    for (int k = 0; k < km; k += 2) {
        int k1 = (k + 1 < km) ? k + 1 : k;
        float m1 = (k + 1 < km) ? 1.f : 0.f;
        const uint4* r0 = (const uint4*)(msg2 + (size_t)(s + k) * 8);
        const uint4* r1 = (const uint4*)(msg2 + (size_t)(s + k1) * 8);
        uint4 A0 = r0[0], B0 = r0[1], A1 = r1[0], B1 = r1[1];
        h[0] += bfl(A0.x) + m1 * bfl(A1.x);  h[1] += bfh(A0.x) + m1 * bfh(A1.x);
        h[2] += bfl(A0.y) + m1 * bfl(A1.y);  h[3] += bfh(A0.y) + m1 * bfh(A1.y);
        h[4] += bfl(A0.z) + m1 * bfl(A1.z);  h[5] += bfh(A0.z) + m1 * bfh(A1.z);
        h[6] += bfl(A0.w) + m1 * bfl(A1.w);  h[7] += bfh(A0.w) + m1 * bfh(A1.w);
        h[8] += bfl(B0.x) + m1 * bfl(B1.x);  h[9] += bfh(B0.x) + m1 * bfh(B1.x);
        h[10] += bfl(B0.y) + m1 * bfl(B1.y); h[11] += bfh(B0.y) + m1 * bfh(B1.y);
        h[12] += bfl(B0.z) + m1 * bfl(B1.z); h[13] += bfh(B0.z) + m1 * bfh(B1.z);
        h[14] += bfl(B0.w) + m1 * bfl(B1.w); h[15] += bfh(B0.w) + m1 * bfh(B1.w);
    }
    float inv = 1.0f / fmaxf((float)cnt, 1.0f);
    float dot = 0.f;
#pragma unroll
    for (int j = 0; j < TYPES; ++j) { h[j] *= inv; dot += h[j] * lw[j]; }
    dot += lb[0];
    float lam = 1.0f / (1.0f + expf(-dot));

    float4* y0 = (float4*)(out + (size_t)nn * TYPES);
    float4* y1 = (float4*)(out + (size_t)N_NODES * TYPES + (size_t)nn * TYPES);
#pragma unroll
    for (int j = 0; j < 4; ++j) {
        float4 v = { h[4*j], h[4*j+1], h[4*j+2], h[4*j+3] };
        y0[j] = v; y1[j] = v;
    }
    out[(size_t)2 * N_NODES * TYPES + nn] = lam;
    out[(size_t)2 * N_NODES * TYPES + N_NODES + nn] = 1.0f - lam;
}

// ---------------------------------------------------------------------------
extern "C" void kernel_launch(void* const* d_in, const int* in_sizes, int n_in,
                              void* d_out, int out_size, void* d_ws, size_t ws_size,
                              hipStream_t stream) {
    const float* entity = (const float*)d_in[0];
    const float* W1     = (const float*)d_in[1];
    const float* W2     = (const float*)d_in[2];
    const float* lw     = (const float*)d_in[3];
    const float* lb     = (const float*)d_in[4];
    const int* src_ids  = (const int*)d_in[5];
    const int* edge_src = (const int*)d_in[6];
    const int* edge_dst = (const int*)d_in[7];
    const int* etype    = (const int*)d_in[8];
    float* out = (float*)d_out;

    // ws layout (u32 units, all 16B aligned)
    unsigned int* W = (unsigned int*)d_ws;
    int* dcnt   = (int*)(W + 0);              // 100000  (zeroed)
    int* rcnt   = (int*)(W + 100000);         // 128     (zeroed)
    uint2* epack = (uint2*)(W + 100128);      // R2*CAP uint2 = 819,200 u32
    unsigned short* pw1 = (unsigned short*)(W + 919328);  // 51,200 u32
    unsigned short* pw2 = (unsigned short*)(W + 970528);  // 25,600 u32
    unsigned int* h1bf  = W + 996128;         // 1.6M u32
    unsigned int* msg1  = W + 2596128;        // N_NODES*CAPD*16 u32 = 25.6M u32
    unsigned int* msg2  = W + 28196128;       // N_NODES*CAPD*8  u32 = 12.8M u32
    // total: 40,996,128 u32 = 164 MB

    (void)hipMemsetAsync(d_ws, 0, 100128 * sizeof(int), stream);  // dcnt+rcnt

    pass1_kernel<<<NB + R2, SB, 0, stream>>>(etype, edge_src, edge_dst, src_ids,
                                             W1, W2, rcnt, dcnt, pw1, pw2, epack);
    layer1_kernel<<<R2 * (S1 / LW), 64 * LW, 0, stream>>>(
        entity, pw1, rcnt, epack, msg1);
    reduce1_kernel<<<(N_NODES * 16 + 255) / 256, 256, 0, stream>>>(msg1, dcnt, h1bf);
    layer2_kernel<<<R2 * (S2 / LW), 64 * LW, 0, stream>>>(
        (const unsigned short*)h1bf, pw2, rcnt, epack, msg2);
    reduce2_head_kernel<<<(N_NODES + 255) / 256, 256, 0, stream>>>(
        msg2, dcnt, lw, lb, out);
}